// Round 16
// baseline (792.228 us; speedup 1.0000x reference)
//
#include <hip/hip_runtime.h>
#include <hip/hip_bf16.h>
#include <cstdint>
#include <cstddef>

// MoE: T=2048 tokens, D=2048, INNER=5632, E=8, top-2 routing (sparse == dense ref).
// R16 = R15 (session-best basin, 706-710 us, 3x reproduced) + T5 s_setprio(1)
// around the MFMA clusters. Mechanism present here (unlike m190's null): the
// gemm1 grid co-schedules pure-VMEM w2-cvt blocks with MFMA GEMM blocks on
// the same CUs -> genuine wave role-split for the scheduler to arbitrate.

#define TOKS  2048
#define DIMSZ 2048
#define INNER 5632
#define NEXP  8

typedef __attribute__((ext_vector_type(8))) short short8;
typedef __attribute__((ext_vector_type(4))) float f32x4;

__device__ __forceinline__ unsigned short f2bf(float f) {
  __hip_bfloat16 b = __float2bfloat16(f);
  return __builtin_bit_cast(unsigned short, b);
}

__device__ __forceinline__ short8 pack8(float4 a, float4 b) {
  short8 s;
  s[0] = (short)f2bf(a.x); s[1] = (short)f2bf(a.y);
  s[2] = (short)f2bf(a.z); s[3] = (short)f2bf(a.w);
  s[4] = (short)f2bf(b.x); s[5] = (short)f2bf(b.y);
  s[6] = (short)f2bf(b.z); s[7] = (short)f2bf(b.w);
  return s;
}

__device__ __forceinline__ short8 pack8v(f32x4 a, f32x4 b) {
  short8 s;
  s[0] = (short)f2bf(a[0]); s[1] = (short)f2bf(a[1]);
  s[2] = (short)f2bf(a[2]); s[3] = (short)f2bf(a[3]);
  s[4] = (short)f2bf(b[0]); s[5] = (short)f2bf(b[1]);
  s[6] = (short)f2bf(b[2]); s[7] = (short)f2bf(b[3]);
  return s;
}

// async global->LDS, 16B/lane; dst is wave-uniform base (HW adds lane*16)
__device__ __forceinline__ void gload16(const unsigned short* src, short8* dst) {
  __builtin_amdgcn_global_load_lds(
      (const __attribute__((address_space(1))) void*)src,
      (__attribute__((address_space(3))) void*)dst, 16, 0, 0);
}
__device__ __forceinline__ void gload16f(const float* src, float4* dst) {
  __builtin_amdgcn_global_load_lds(
      (const __attribute__((address_space(1))) void*)src,
      (__attribute__((address_space(3))) void*)dst, 16, 0, 0);
}

// ---------------- router -----------------------------------------------------
__global__ void __launch_bounds__(64)
router_kernel(const float* __restrict__ x, const float* __restrict__ gw,
              int* __restrict__ sel, float* __restrict__ wts) {
  const int t = blockIdx.x;
  const int l = threadIdx.x;
  const float* xr = x + (size_t)t * DIMSZ;
  float xv[32];
#pragma unroll
  for (int i = 0; i < 32; ++i) xv[i] = xr[l + 64 * i];
  float lg[NEXP];
#pragma unroll
  for (int e = 0; e < NEXP; ++e) {
    const float* gr = gw + e * DIMSZ;
    float s = 0.f;
#pragma unroll
    for (int i = 0; i < 32; ++i) s += xv[i] * gr[l + 64 * i];
#pragma unroll
    for (int off = 32; off > 0; off >>= 1) s += __shfl_down(s, off, 64);
    lg[e] = s;
  }
  if (l == 0) {
    float m = lg[0];
#pragma unroll
    for (int e = 1; e < NEXP; ++e) m = fmaxf(m, lg[e]);
    float p[NEXP];
#pragma unroll
    for (int e = 0; e < NEXP; ++e) p[e] = __expf(lg[e] - m);
    int i1 = 0;
#pragma unroll
    for (int e = 1; e < NEXP; ++e) if (p[e] > p[i1]) i1 = e;
    int i2 = (i1 == 0) ? 1 : 0;
#pragma unroll
    for (int e = 0; e < NEXP; ++e) if (e != i1 && p[e] > p[i2]) i2 = e;
    float den = p[i1] + p[i2];
    sel[2 * t] = i1; sel[2 * t + 1] = i2;
    wts[2 * t] = p[i1] / den; wts[2 * t + 1] = p[i2] / den;
  }
}

// ---- compaction -------------------------------------------------------------
__global__ void __launch_bounds__(512)
compact_kernel(const int* __restrict__ sel, const float* __restrict__ wts,
               int* __restrict__ cnt, int* __restrict__ offs,
               int* __restrict__ tok, float* __restrict__ twt) {
  const int w = threadIdx.x >> 6;
  const int l = threadIdx.x & 63;
  int c = 0;
  for (int base = 0; base < 2 * TOKS; base += 64) {
    int s = base + l;
    bool m = (sel[s] == w);
    unsigned long long mask = __ballot(m);
    int pre = __popcll(mask & ((1ull << l) - 1ull));
    if (m) {
      tok[w * TOKS + c + pre] = s >> 1;
      twt[w * TOKS + c + pre] = wts[s];
    }
    c += __popcll(mask);
  }
  if (l == 0) cnt[w] = c;
  __syncthreads();
  if (threadIdx.x == 0) {
    int acc = 0;
    for (int e = 0; e < NEXP; ++e) { offs[e] = acc; acc += cnt[e]; }
  }
}

// ---------------- x fp32 -> bf16 ---------------------------------------------
__global__ void __launch_bounds__(256)
cvtx_kernel(const float* __restrict__ x, unsigned short* __restrict__ xbf) {
  const int i = blockIdx.x * 256 + threadIdx.x;
  const f32x4* src = (const f32x4*)x;
  f32x4 a = __builtin_nontemporal_load(src + 2 * i);        // x read-once
  f32x4 b = __builtin_nontemporal_load(src + 2 * i + 1);
  ((short8*)xbf)[i] = pack8v(a, b);                         // xbf reused: normal
}

// ------- GEMM1 (direct fp32 weights): h = silu(x·w1^T) * (x·w3^T) -----------
// 128(M)x64(N), BK=64, 256 thr / 4 waves (2Mx2N), m97 single-buffer 2-barrier
// loop, 48KB LDS -> 3 blocks/CU, XCD panel-major remap, fp32 B staged via
// global_load_lds with in-fragment cvt, w2->bf16 conversion blocks
// interleaved (2 of every 13 per-XCD slots) with NONTEMPORAL streams.
// T5: setprio(1) around the MFMA cluster (role-split vs cvt waves present).
__global__ void __launch_bounds__(256, 3)
gemm1_fw(const unsigned short* __restrict__ xbf,
         const float* __restrict__ w1, const float* __restrict__ w3,
         const float* __restrict__ w2, unsigned short* __restrict__ w2bf,
         const int* __restrict__ cnt, const int* __restrict__ offs,
         const int* __restrict__ tok, unsigned short* __restrict__ h) {
  const int tid = threadIdx.x;
  // per-XCD slot decode: bid -> (xcd, slot); 1664 slots/XCD; slot%13>=11 -> cvt
  const int xcd = blockIdx.x & 7;
  const int s   = blockIdx.x >> 3;          // 0..1663
  const int q13 = s / 13, r13 = s % 13;

  if (r13 >= 11) {                          // ---- interleaved w2 fp32->bf16 --
    // nontemporal: w2 read once, w2bf not read until gemm2 -> bypass L2 so
    // this 553 MB stream stops evicting the w1/w3 panels gemm1 reuses.
    const int idx = xcd * 256 + q13 * 2 + (r13 - 11);   // 0..2047
    const int n8 = (int)(((size_t)NEXP * DIMSZ * INNER) / 8);  // 11,534,336
    for (int i = idx * 256 + tid; i < n8; i += 2048 * 256) {
      const f32x4* sp = (const f32x4*)w2 + 2 * (size_t)i;
      f32x4 a = __builtin_nontemporal_load(sp);
      f32x4 b = __builtin_nontemporal_load(sp + 1);
      __builtin_nontemporal_store(pack8v(a, b), (short8*)w2bf + i);
    }
    return;
  }

  // GEMM slot: contiguous panel-major run within this XCD
  const int lid = xcd * 1408 + q13 * 11 + r13;   // 0..11263
  const int my = lid & 15;             // M-slot (panel-mates adjacent in lid)
  const int e  = (lid >> 4) & 7;
  const int bx = lid >> 7;             // 0..87 N-panel
  const int n_e = cnt[e];
  if (n_e == 0 || my * 128 >= n_e) return;
  const int n0 = bx * 64;
  const int lane = tid & 63;
  const int wid = tid >> 6;
  const int wm = wid >> 1, wn = wid & 1;

  __shared__ short8 As[1024];    // 128 rows x 8 bf16-groups (16KB)
  __shared__ float4 B1s[1024];   // 64 rows x 16 f32-groups (16KB)
  __shared__ float4 B3s[1024];   // total 48KB -> 3 blocks/CU

  // A: per-lane pre-swizzled source (g ^ row&7), linear LDS dest
  const unsigned short* aptr[4];
#pragma unroll
  for (int i = 0; i < 4; ++i) {
    int sl = i * 256 + wid * 64 + lane;
    int row = sl >> 3, g = sl & 7;
    int ri = my * 128 + row; if (ri >= n_e) ri = n_e - 1;
    int tkn = tok[e * TOKS + ri];
    aptr[i] = xbf + (size_t)tkn * DIMSZ + ((g ^ (row & 7)) * 8);
  }
  // B fp32: 64 rows x 16 groups of 4 floats; source col-group = gg ^ (row&15)
  const float* b1p[4]; const float* b3p[4];
#pragma unroll
  for (int i = 0; i < 4; ++i) {
    int sl = i * 256 + wid * 64 + lane;
    int row = sl >> 4, gg = sl & 15;
    size_t off = (size_t)e * INNER * DIMSZ + (size_t)(n0 + row) * DIMSZ
               + ((gg ^ (row & 15)) * 4);
    b1p[i] = w1 + off;
    b3p[i] = w3 + off;
  }

  f32x4 acc1[4][2] = {};
  f32x4 acc3[4][2] = {};

  for (int k0 = 0; k0 < DIMSZ; k0 += 64) {
    // B first: the HBM-heavy stream gets its first-byte latency started early
#pragma unroll
    for (int i = 0; i < 4; ++i) {
      gload16f(b1p[i] + k0, &B1s[i * 256 + wid * 64]);
      gload16f(b3p[i] + k0, &B3s[i * 256 + wid * 64]);
    }
#pragma unroll
    for (int i = 0; i < 4; ++i) gload16(aptr[i] + k0, &As[i * 256 + wid * 64]);
    __syncthreads();
#pragma unroll
    for (int ks = 0; ks < 2; ++ks) {
      const int kg = ks * 4 + (lane >> 4);
      short8 af[4], b1f[2], b3f[2];
#pragma unroll
      for (int m = 0; m < 4; ++m) {
        int row = wm * 64 + m * 16 + (lane & 15);
        af[m] = As[row * 8 + (kg ^ (row & 7))];
      }
#pragma unroll
      for (int n = 0; n < 2; ++n) {
        int row = wn * 32 + n * 16 + (lane & 15);
        int base = row * 16;
        int sw = row & 15;
        float4 u0 = B1s[base + ((2 * kg) ^ sw)];
        float4 u1 = B1s[base + ((2 * kg + 1) ^ sw)];
        b1f[n] = pack8(u0, u1);
        float4 v0 = B3s[base + ((2 * kg) ^ sw)];
        float4 v1 = B3s[base + ((2 * kg + 1) ^ sw)];
        b3f[n] = pack8(v0, v1);
      }
      __builtin_amdgcn_s_setprio(1);    // T5: favor MFMA waves vs cvt waves
#pragma unroll
      for (int m = 0; m < 4; ++m)
#pragma unroll
        for (int n = 0; n < 2; ++n) {
          acc1[m][n] = __builtin_amdgcn_mfma_f32_16x16x32_bf16(af[m], b1f[n], acc1[m][n], 0, 0, 0);
          acc3[m][n] = __builtin_amdgcn_mfma_f32_16x16x32_bf16(af[m], b3f[n], acc3[m][n], 0, 0, 0);
        }
      __builtin_amdgcn_s_setprio(0);
    }
    __syncthreads();
  }

  const int obase = offs[e];
#pragma unroll
  for (int m = 0; m < 4; ++m)
#pragma unroll
    for (int r = 0; r < 4; ++r) {
      int i = my * 128 + wm * 64 + m * 16 + (lane >> 4) * 4 + r;
      if (i < n_e) {
        unsigned short* hp = h + (size_t)(obase + i) * INNER + n0 + wn * 32 + (lane & 15);
#pragma unroll
        for (int n = 0; n < 2; ++n) {
          float v1 = acc1[m][n][r];
          float v3 = acc3[m][n][r];
          float hv = __fdividef(v1, 1.f + __expf(-v1)) * v3;
          hp[n * 16] = f2bf(hv);
        }
      }
    }
}

// ------- GEMM2 (bf16 w2): out[t] += wt * (h · w2^T) -------------------------
// 256(M)x128(N), BK=64, 512 thr / 8 waves (4Mx2N, 64x64 each), single-buffer
// 2-barrier, XCD-bijective remap, 48KB LDS. T5 setprio on MFMA cluster.
__global__ void __launch_bounds__(512, 4)
gemm2_bf(const unsigned short* __restrict__ h, const unsigned short* __restrict__ w2b,
         const int* __restrict__ cnt, const int* __restrict__ offs,
         const int* __restrict__ tok, const float* __restrict__ twt,
         float* __restrict__ out) {
  const int NWG   = (DIMSZ / 128) * NEXP * 8;    // 1024
  const int CHUNK = NWG / 8;                     // 128
  const int lid = (blockIdx.x & 7) * CHUNK + (blockIdx.x >> 3);
  const int my = lid & 7;              // M-slot (256 rows each)
  const int e  = (lid >> 3) & 7;
  const int bx = lid >> 6;             // 0..15
  const int n_e = cnt[e];
  if (n_e == 0 || my * 256 >= n_e) return;
  const int n0 = bx * 128;
  const int tid = threadIdx.x;
  const int lane = tid & 63;
  const int wid = tid >> 6;
  const int wm = wid >> 1, wn = wid & 1;   // wm 0..3, wn 0..1
  const int obase = offs[e];

  __shared__ short8 As[2048];   // 256 rows x 8 groups (32KB)
  __shared__ short8 Bs[1024];   // 128 rows x 8 groups (16KB)

  const unsigned short* aptr[4];
#pragma unroll
  for (int i = 0; i < 4; ++i) {
    int sl = i * 512 + wid * 64 + lane;
    int row = sl >> 3, g = sl & 7;
    int ri = my * 256 + row; if (ri >= n_e) ri = n_e - 1;
    aptr[i] = h + (size_t)(obase + ri) * INNER + ((g ^ (row & 7)) * 8);
  }
  const unsigned short* bptr[2];
#pragma unroll
  for (int i = 0; i < 2; ++i) {
    int sl = i * 512 + wid * 64 + lane;
    int row = sl >> 3, g = sl & 7;
    bptr[i] = w2b + (size_t)e * DIMSZ * INNER + (size_t)(n0 + row) * INNER + (g ^ (row & 7)) * 8;
  }

  f32x4 acc[4][4] = {};

  for (int k0 = 0; k0 < INNER; k0 += 64) {
#pragma unroll
    for (int i = 0; i < 4; ++i) gload16(aptr[i] + k0, &As[i * 512 + wid * 64]);
#pragma unroll
    for (int i = 0; i < 2; ++i) gload16(bptr[i] + k0, &Bs[i * 512 + wid * 64]);
    __syncthreads();
#pragma unroll
    for (int ks = 0; ks < 2; ++ks) {
      const int kg = ks * 4 + (lane >> 4);
      short8 af[4], bf[4];
#pragma unroll
      for (int m = 0; m < 4; ++m) {
        int row = wm * 64 + m * 16 + (lane & 15);
        af[m] = As[row * 8 + (kg ^ (row & 7))];
      }
#pragma unroll
      for (int n = 0; n < 4; ++n) {
        int row = wn * 64 + n * 16 + (lane & 15);
        bf[n] = Bs[row * 8 + (kg ^ (row & 7))];
      }
      __builtin_amdgcn_s_setprio(1);
#pragma unroll
      for (int m = 0; m < 4; ++m)
#pragma unroll
        for (int n = 0; n < 4; ++n)
          acc[m][n] = __builtin_amdgcn_mfma_f32_16x16x32_bf16(af[m], bf[n], acc[m][n], 0, 0, 0);
      __builtin_amdgcn_s_setprio(0);
    }
    __syncthreads();
  }

#pragma unroll
  for (int m = 0; m < 4; ++m)
#pragma unroll
    for (int r = 0; r < 4; ++r) {
      int i = my * 256 + wm * 64 + m * 16 + (lane >> 4) * 4 + r;
      if (i < n_e) {
        int t = tok[e * TOKS + i];
        float wt = twt[e * TOKS + i];
        float* op = out + (size_t)t * DIMSZ + n0 + wn * 64 + (lane & 15);
#pragma unroll
        for (int n = 0; n < 4; ++n)
          atomicAdd(op + n * 16, acc[m][n][r] * wt);
      }
    }
}

// ---------------------------------------------------------------------------
extern "C" void kernel_launch(void* const* d_in, const int* in_sizes, int n_in,
                              void* d_out, int out_size, void* d_ws, size_t ws_size,
                              hipStream_t stream) {
  (void)in_sizes; (void)n_in; (void)ws_size;
  const float* x  = (const float*)d_in[0];
  const float* gw = (const float*)d_in[1];
  const float* w1 = (const float*)d_in[2];
  const float* w2 = (const float*)d_in[3];
  const float* w3 = (const float*)d_in[4];
  float* out = (float*)d_out;

  char* ws = (char*)d_ws;
  int*            sel  = (int*)(ws);
  float*          wts  = (float*)(ws + (16 << 10));
  int*            cnt  = (int*)(ws + (32 << 10));
  int*            offs = (int*)(ws + (32 << 10) + 64);
  int*            tok  = (int*)(ws + (33 << 10));
  float*          twt  = (float*)(ws + (97 << 10));
  unsigned short* xbf  = (unsigned short*)(ws + (1 << 20));   // 8.4 MB
  unsigned short* h    = (unsigned short*)(ws + (16 << 20));  // 46.2 MB
  unsigned short* w2bf = (unsigned short*)(ws + (64ull << 20));  // 184.5 MB

  hipMemsetAsync(out, 0, (size_t)out_size * sizeof(float), stream);
  cvtx_kernel<<<2048, 256, 0, stream>>>(x, xbf);
  router_kernel<<<TOKS, 64, 0, stream>>>(x, gw, sel, wts);
  compact_kernel<<<1, 512, 0, stream>>>(sel, wts, cnt, offs, tok, twt);

  // gemm1: 11264 GEMM blocks + 2048 interleaved w2-cvt blocks = 13312
  gemm1_fw<<<13312, 256, 0, stream>>>(
      xbf, w1, w3, w2, w2bf, cnt, offs, tok, h);
  gemm2_bf<<<(DIMSZ / 128) * NEXP * 8, 512, 0, stream>>>(
      h, w2bf, cnt, offs, tok, twt, out);
}

// Round 17
// 706.342 us; speedup vs baseline: 1.1216x; 1.1216x over previous
//
#include <hip/hip_runtime.h>
#include <hip/hip_bf16.h>
#include <cstdint>
#include <cstddef>

// MoE: T=2048 tokens, D=2048, INNER=5632, E=8, top-2 routing (sparse == dense ref).
// R17 = R16 with T5 setprio KEPT in gemm1_fw (role-split vs cvt waves present,
// measured -11us) and REMOVED from gemm2_bf (lockstep 8-wave kernel, no role
// diversity -> setprio regressed it ~+90us, consistent with m190).

#define TOKS  2048
#define DIMSZ 2048
#define INNER 5632
#define NEXP  8

typedef __attribute__((ext_vector_type(8))) short short8;
typedef __attribute__((ext_vector_type(4))) float f32x4;

__device__ __forceinline__ unsigned short f2bf(float f) {
  __hip_bfloat16 b = __float2bfloat16(f);
  return __builtin_bit_cast(unsigned short, b);
}

__device__ __forceinline__ short8 pack8(float4 a, float4 b) {
  short8 s;
  s[0] = (short)f2bf(a.x); s[1] = (short)f2bf(a.y);
  s[2] = (short)f2bf(a.z); s[3] = (short)f2bf(a.w);
  s[4] = (short)f2bf(b.x); s[5] = (short)f2bf(b.y);
  s[6] = (short)f2bf(b.z); s[7] = (short)f2bf(b.w);
  return s;
}

__device__ __forceinline__ short8 pack8v(f32x4 a, f32x4 b) {
  short8 s;
  s[0] = (short)f2bf(a[0]); s[1] = (short)f2bf(a[1]);
  s[2] = (short)f2bf(a[2]); s[3] = (short)f2bf(a[3]);
  s[4] = (short)f2bf(b[0]); s[5] = (short)f2bf(b[1]);
  s[6] = (short)f2bf(b[2]); s[7] = (short)f2bf(b[3]);
  return s;
}

// async global->LDS, 16B/lane; dst is wave-uniform base (HW adds lane*16)
__device__ __forceinline__ void gload16(const unsigned short* src, short8* dst) {
  __builtin_amdgcn_global_load_lds(
      (const __attribute__((address_space(1))) void*)src,
      (__attribute__((address_space(3))) void*)dst, 16, 0, 0);
}
__device__ __forceinline__ void gload16f(const float* src, float4* dst) {
  __builtin_amdgcn_global_load_lds(
      (const __attribute__((address_space(1))) void*)src,
      (__attribute__((address_space(3))) void*)dst, 16, 0, 0);
}

// ---------------- router -----------------------------------------------------
__global__ void __launch_bounds__(64)
router_kernel(const float* __restrict__ x, const float* __restrict__ gw,
              int* __restrict__ sel, float* __restrict__ wts) {
  const int t = blockIdx.x;
  const int l = threadIdx.x;
  const float* xr = x + (size_t)t * DIMSZ;
  float xv[32];
#pragma unroll
  for (int i = 0; i < 32; ++i) xv[i] = xr[l + 64 * i];
  float lg[NEXP];
#pragma unroll
  for (int e = 0; e < NEXP; ++e) {
    const float* gr = gw + e * DIMSZ;
    float s = 0.f;
#pragma unroll
    for (int i = 0; i < 32; ++i) s += xv[i] * gr[l + 64 * i];
#pragma unroll
    for (int off = 32; off > 0; off >>= 1) s += __shfl_down(s, off, 64);
    lg[e] = s;
  }
  if (l == 0) {
    float m = lg[0];
#pragma unroll
    for (int e = 1; e < NEXP; ++e) m = fmaxf(m, lg[e]);
    float p[NEXP];
#pragma unroll
    for (int e = 0; e < NEXP; ++e) p[e] = __expf(lg[e] - m);
    int i1 = 0;
#pragma unroll
    for (int e = 1; e < NEXP; ++e) if (p[e] > p[i1]) i1 = e;
    int i2 = (i1 == 0) ? 1 : 0;
#pragma unroll
    for (int e = 0; e < NEXP; ++e) if (e != i1 && p[e] > p[i2]) i2 = e;
    float den = p[i1] + p[i2];
    sel[2 * t] = i1; sel[2 * t + 1] = i2;
    wts[2 * t] = p[i1] / den; wts[2 * t + 1] = p[i2] / den;
  }
}

// ---- compaction -------------------------------------------------------------
__global__ void __launch_bounds__(512)
compact_kernel(const int* __restrict__ sel, const float* __restrict__ wts,
               int* __restrict__ cnt, int* __restrict__ offs,
               int* __restrict__ tok, float* __restrict__ twt) {
  const int w = threadIdx.x >> 6;
  const int l = threadIdx.x & 63;
  int c = 0;
  for (int base = 0; base < 2 * TOKS; base += 64) {
    int s = base + l;
    bool m = (sel[s] == w);
    unsigned long long mask = __ballot(m);
    int pre = __popcll(mask & ((1ull << l) - 1ull));
    if (m) {
      tok[w * TOKS + c + pre] = s >> 1;
      twt[w * TOKS + c + pre] = wts[s];
    }
    c += __popcll(mask);
  }
  if (l == 0) cnt[w] = c;
  __syncthreads();
  if (threadIdx.x == 0) {
    int acc = 0;
    for (int e = 0; e < NEXP; ++e) { offs[e] = acc; acc += cnt[e]; }
  }
}

// ---------------- x fp32 -> bf16 ---------------------------------------------
__global__ void __launch_bounds__(256)
cvtx_kernel(const float* __restrict__ x, unsigned short* __restrict__ xbf) {
  const int i = blockIdx.x * 256 + threadIdx.x;
  const f32x4* src = (const f32x4*)x;
  f32x4 a = __builtin_nontemporal_load(src + 2 * i);        // x read-once
  f32x4 b = __builtin_nontemporal_load(src + 2 * i + 1);
  ((short8*)xbf)[i] = pack8v(a, b);                         // xbf reused: normal
}

// ------- GEMM1 (direct fp32 weights): h = silu(x·w1^T) * (x·w3^T) -----------
// 128(M)x64(N), BK=64, 256 thr / 4 waves (2Mx2N), m97 single-buffer 2-barrier
// loop, 48KB LDS -> 3 blocks/CU, XCD panel-major remap, fp32 B staged via
// global_load_lds with in-fragment cvt, w2->bf16 conversion blocks
// interleaved (2 of every 13 per-XCD slots) with NONTEMPORAL streams.
// T5: setprio(1) around the MFMA cluster (role-split vs cvt waves present).
__global__ void __launch_bounds__(256, 3)
gemm1_fw(const unsigned short* __restrict__ xbf,
         const float* __restrict__ w1, const float* __restrict__ w3,
         const float* __restrict__ w2, unsigned short* __restrict__ w2bf,
         const int* __restrict__ cnt, const int* __restrict__ offs,
         const int* __restrict__ tok, unsigned short* __restrict__ h) {
  const int tid = threadIdx.x;
  // per-XCD slot decode: bid -> (xcd, slot); 1664 slots/XCD; slot%13>=11 -> cvt
  const int xcd = blockIdx.x & 7;
  const int s   = blockIdx.x >> 3;          // 0..1663
  const int q13 = s / 13, r13 = s % 13;

  if (r13 >= 11) {                          // ---- interleaved w2 fp32->bf16 --
    // nontemporal: w2 read once, w2bf not read until gemm2 -> bypass L2 so
    // this 553 MB stream stops evicting the w1/w3 panels gemm1 reuses.
    const int idx = xcd * 256 + q13 * 2 + (r13 - 11);   // 0..2047
    const int n8 = (int)(((size_t)NEXP * DIMSZ * INNER) / 8);  // 11,534,336
    for (int i = idx * 256 + tid; i < n8; i += 2048 * 256) {
      const f32x4* sp = (const f32x4*)w2 + 2 * (size_t)i;
      f32x4 a = __builtin_nontemporal_load(sp);
      f32x4 b = __builtin_nontemporal_load(sp + 1);
      __builtin_nontemporal_store(pack8v(a, b), (short8*)w2bf + i);
    }
    return;
  }

  // GEMM slot: contiguous panel-major run within this XCD
  const int lid = xcd * 1408 + q13 * 11 + r13;   // 0..11263
  const int my = lid & 15;             // M-slot (panel-mates adjacent in lid)
  const int e  = (lid >> 4) & 7;
  const int bx = lid >> 7;             // 0..87 N-panel
  const int n_e = cnt[e];
  if (n_e == 0 || my * 128 >= n_e) return;
  const int n0 = bx * 64;
  const int lane = tid & 63;
  const int wid = tid >> 6;
  const int wm = wid >> 1, wn = wid & 1;

  __shared__ short8 As[1024];    // 128 rows x 8 bf16-groups (16KB)
  __shared__ float4 B1s[1024];   // 64 rows x 16 f32-groups (16KB)
  __shared__ float4 B3s[1024];   // total 48KB -> 3 blocks/CU

  // A: per-lane pre-swizzled source (g ^ row&7), linear LDS dest
  const unsigned short* aptr[4];
#pragma unroll
  for (int i = 0; i < 4; ++i) {
    int sl = i * 256 + wid * 64 + lane;
    int row = sl >> 3, g = sl & 7;
    int ri = my * 128 + row; if (ri >= n_e) ri = n_e - 1;
    int tkn = tok[e * TOKS + ri];
    aptr[i] = xbf + (size_t)tkn * DIMSZ + ((g ^ (row & 7)) * 8);
  }
  // B fp32: 64 rows x 16 groups of 4 floats; source col-group = gg ^ (row&15)
  const float* b1p[4]; const float* b3p[4];
#pragma unroll
  for (int i = 0; i < 4; ++i) {
    int sl = i * 256 + wid * 64 + lane;
    int row = sl >> 4, gg = sl & 15;
    size_t off = (size_t)e * INNER * DIMSZ + (size_t)(n0 + row) * DIMSZ
               + ((gg ^ (row & 15)) * 4);
    b1p[i] = w1 + off;
    b3p[i] = w3 + off;
  }

  f32x4 acc1[4][2] = {};
  f32x4 acc3[4][2] = {};

  for (int k0 = 0; k0 < DIMSZ; k0 += 64) {
    // B first: the HBM-heavy stream gets its first-byte latency started early
#pragma unroll
    for (int i = 0; i < 4; ++i) {
      gload16f(b1p[i] + k0, &B1s[i * 256 + wid * 64]);
      gload16f(b3p[i] + k0, &B3s[i * 256 + wid * 64]);
    }
#pragma unroll
    for (int i = 0; i < 4; ++i) gload16(aptr[i] + k0, &As[i * 256 + wid * 64]);
    __syncthreads();
#pragma unroll
    for (int ks = 0; ks < 2; ++ks) {
      const int kg = ks * 4 + (lane >> 4);
      short8 af[4], b1f[2], b3f[2];
#pragma unroll
      for (int m = 0; m < 4; ++m) {
        int row = wm * 64 + m * 16 + (lane & 15);
        af[m] = As[row * 8 + (kg ^ (row & 7))];
      }
#pragma unroll
      for (int n = 0; n < 2; ++n) {
        int row = wn * 32 + n * 16 + (lane & 15);
        int base = row * 16;
        int sw = row & 15;
        float4 u0 = B1s[base + ((2 * kg) ^ sw)];
        float4 u1 = B1s[base + ((2 * kg + 1) ^ sw)];
        b1f[n] = pack8(u0, u1);
        float4 v0 = B3s[base + ((2 * kg) ^ sw)];
        float4 v1 = B3s[base + ((2 * kg + 1) ^ sw)];
        b3f[n] = pack8(v0, v1);
      }
      __builtin_amdgcn_s_setprio(1);    // T5: favor MFMA waves vs cvt waves
#pragma unroll
      for (int m = 0; m < 4; ++m)
#pragma unroll
        for (int n = 0; n < 2; ++n) {
          acc1[m][n] = __builtin_amdgcn_mfma_f32_16x16x32_bf16(af[m], b1f[n], acc1[m][n], 0, 0, 0);
          acc3[m][n] = __builtin_amdgcn_mfma_f32_16x16x32_bf16(af[m], b3f[n], acc3[m][n], 0, 0, 0);
        }
      __builtin_amdgcn_s_setprio(0);
    }
    __syncthreads();
  }

  const int obase = offs[e];
#pragma unroll
  for (int m = 0; m < 4; ++m)
#pragma unroll
    for (int r = 0; r < 4; ++r) {
      int i = my * 128 + wm * 64 + m * 16 + (lane >> 4) * 4 + r;
      if (i < n_e) {
        unsigned short* hp = h + (size_t)(obase + i) * INNER + n0 + wn * 32 + (lane & 15);
#pragma unroll
        for (int n = 0; n < 2; ++n) {
          float v1 = acc1[m][n][r];
          float v3 = acc3[m][n][r];
          float hv = __fdividef(v1, 1.f + __expf(-v1)) * v3;
          hp[n * 16] = f2bf(hv);
        }
      }
    }
}

// ------- GEMM2 (bf16 w2): out[t] += wt * (h · w2^T) -------------------------
// 256(M)x128(N), BK=64, 512 thr / 8 waves (4Mx2N, 64x64 each), single-buffer
// 2-barrier, XCD-bijective remap, 48KB LDS. NO setprio (lockstep waves,
// mechanism absent -> R16 measured it regressing ~+90us).
__global__ void __launch_bounds__(512, 4)
gemm2_bf(const unsigned short* __restrict__ h, const unsigned short* __restrict__ w2b,
         const int* __restrict__ cnt, const int* __restrict__ offs,
         const int* __restrict__ tok, const float* __restrict__ twt,
         float* __restrict__ out) {
  const int NWG   = (DIMSZ / 128) * NEXP * 8;    // 1024
  const int CHUNK = NWG / 8;                     // 128
  const int lid = (blockIdx.x & 7) * CHUNK + (blockIdx.x >> 3);
  const int my = lid & 7;              // M-slot (256 rows each)
  const int e  = (lid >> 3) & 7;
  const int bx = lid >> 6;             // 0..15
  const int n_e = cnt[e];
  if (n_e == 0 || my * 256 >= n_e) return;
  const int n0 = bx * 128;
  const int tid = threadIdx.x;
  const int lane = tid & 63;
  const int wid = tid >> 6;
  const int wm = wid >> 1, wn = wid & 1;   // wm 0..3, wn 0..1
  const int obase = offs[e];

  __shared__ short8 As[2048];   // 256 rows x 8 groups (32KB)
  __shared__ short8 Bs[1024];   // 128 rows x 8 groups (16KB)

  const unsigned short* aptr[4];
#pragma unroll
  for (int i = 0; i < 4; ++i) {
    int sl = i * 512 + wid * 64 + lane;
    int row = sl >> 3, g = sl & 7;
    int ri = my * 256 + row; if (ri >= n_e) ri = n_e - 1;
    aptr[i] = h + (size_t)(obase + ri) * INNER + ((g ^ (row & 7)) * 8);
  }
  const unsigned short* bptr[2];
#pragma unroll
  for (int i = 0; i < 2; ++i) {
    int sl = i * 512 + wid * 64 + lane;
    int row = sl >> 3, g = sl & 7;
    bptr[i] = w2b + (size_t)e * DIMSZ * INNER + (size_t)(n0 + row) * INNER + (g ^ (row & 7)) * 8;
  }

  f32x4 acc[4][4] = {};

  for (int k0 = 0; k0 < INNER; k0 += 64) {
#pragma unroll
    for (int i = 0; i < 4; ++i) gload16(aptr[i] + k0, &As[i * 512 + wid * 64]);
#pragma unroll
    for (int i = 0; i < 2; ++i) gload16(bptr[i] + k0, &Bs[i * 512 + wid * 64]);
    __syncthreads();
#pragma unroll
    for (int ks = 0; ks < 2; ++ks) {
      const int kg = ks * 4 + (lane >> 4);
      short8 af[4], bf[4];
#pragma unroll
      for (int m = 0; m < 4; ++m) {
        int row = wm * 64 + m * 16 + (lane & 15);
        af[m] = As[row * 8 + (kg ^ (row & 7))];
      }
#pragma unroll
      for (int n = 0; n < 4; ++n) {
        int row = wn * 64 + n * 16 + (lane & 15);
        bf[n] = Bs[row * 8 + (kg ^ (row & 7))];
      }
#pragma unroll
      for (int m = 0; m < 4; ++m)
#pragma unroll
        for (int n = 0; n < 4; ++n)
          acc[m][n] = __builtin_amdgcn_mfma_f32_16x16x32_bf16(af[m], bf[n], acc[m][n], 0, 0, 0);
    }
    __syncthreads();
  }

#pragma unroll
  for (int m = 0; m < 4; ++m)
#pragma unroll
    for (int r = 0; r < 4; ++r) {
      int i = my * 256 + wm * 64 + m * 16 + (lane >> 4) * 4 + r;
      if (i < n_e) {
        int t = tok[e * TOKS + i];
        float wt = twt[e * TOKS + i];
        float* op = out + (size_t)t * DIMSZ + n0 + wn * 64 + (lane & 15);
#pragma unroll
        for (int n = 0; n < 4; ++n)
          atomicAdd(op + n * 16, acc[m][n][r] * wt);
      }
    }
}

// ---------------------------------------------------------------------------
extern "C" void kernel_launch(void* const* d_in, const int* in_sizes, int n_in,
                              void* d_out, int out_size, void* d_ws, size_t ws_size,
                              hipStream_t stream) {
  (void)in_sizes; (void)n_in; (void)ws_size;
  const float* x  = (const float*)d_in[0];
  const float* gw = (const float*)d_in[1];
  const float* w1 = (const float*)d_in[2];
  const float* w2 = (const float*)d_in[3];
  const float* w3 = (const float*)d_in[4];
  float* out = (float*)d_out;

  char* ws = (char*)d_ws;
  int*            sel  = (int*)(ws);
  float*          wts  = (float*)(ws + (16 << 10));
  int*            cnt  = (int*)(ws + (32 << 10));
  int*            offs = (int*)(ws + (32 << 10) + 64);
  int*            tok  = (int*)(ws + (33 << 10));
  float*          twt  = (float*)(ws + (97 << 10));
  unsigned short* xbf  = (unsigned short*)(ws + (1 << 20));   // 8.4 MB
  unsigned short* h    = (unsigned short*)(ws + (16 << 20));  // 46.2 MB
  unsigned short* w2bf = (unsigned short*)(ws + (64ull << 20));  // 184.5 MB

  hipMemsetAsync(out, 0, (size_t)out_size * sizeof(float), stream);
  cvtx_kernel<<<2048, 256, 0, stream>>>(x, xbf);
  router_kernel<<<TOKS, 64, 0, stream>>>(x, gw, sel, wts);
  compact_kernel<<<1, 512, 0, stream>>>(sel, wts, cnt, offs, tok, twt);

  // gemm1: 11264 GEMM blocks + 2048 interleaved w2-cvt blocks = 13312
  gemm1_fw<<<13312, 256, 0, stream>>>(
      xbf, w1, w3, w2, w2bf, cnt, offs, tok, h);
  gemm2_bf<<<(DIMSZ / 128) * NEXP * 8, 512, 0, stream>>>(
      h, w2bf, cnt, offs, tok, twt, out);
}